// Round 3
// baseline (353.772 us; speedup 1.0000x reference)
//
#include <hip/hip_runtime.h>

// ---- problem constants ----
#define M_IMG 1008
#define N_PCD 1024
#define CDIM  256
#define NI_F  76800
#define NP_F  30000
#define KI    64
#define KP    64
#define NUM_CORR 256
#define NPAIR (NUM_CORR * KI)       // 16384
#define KEY_MOD 30001u
#define NCAND (M_IMG * 3)           // 3024 candidate slots
#define NEG_INF (-__builtin_inff())

// bool inputs may arrive as uint8 (numpy bool) or int32 layouts.
// Detected per-block: scan first 256 words of pcd_knn_msk; u8 layout has
// set bytes above byte 0 in nearly every word (~90% true masks).
__device__ __forceinline__ bool mask_val(const void* p, int i, int is_u8) {
    return is_u8 ? (((const unsigned char*)p)[i] != 0)
                 : (((const int*)p)[i] != 0);
}

// ---- top-3 helpers (values only, multiplicity preserved) ----
__device__ __forceinline__ void top3_insert(float v, float& t0, float& t1, float& t2) {
    if (v > t0) { t2 = t1; t1 = t0; t0 = v; }
    else if (v > t1) { t2 = t1; t1 = v; }
    else if (v > t2) { t2 = v; }
}

__device__ __forceinline__ void top3_merge(float a0, float a1, float a2,
                                           float b0, float b1, float b2,
                                           float& x0, float& x1, float& x2) {
    if (a0 >= b0) {
        x0 = a0;
        if (a1 >= b0) { x1 = a1; x2 = (a2 >= b0) ? a2 : b0; }
        else          { x1 = b0; x2 = (a1 >= b1) ? a1 : b1; }
    } else {
        x0 = b0;
        if (b1 >= a0) { x1 = b1; x2 = (b2 >= a0) ? b2 : a0; }
        else          { x1 = a0; x2 = (b1 >= a1) ? b1 : a1; }
    }
}

// top-3 with index tracking
__device__ __forceinline__ void t3i_insert(float v, int i,
                                           float& v0, int& i0,
                                           float& v1, int& i1,
                                           float& v2, int& i2) {
    if (v > v0) { v2 = v1; i2 = i1; v1 = v0; i1 = i0; v0 = v; i0 = i; }
    else if (v > v1) { v2 = v1; i2 = i1; v1 = v; i1 = i; }
    else if (v > v2) { v2 = v; i2 = i; }
}

// =====================================================================
// Kernel 1: coarse sim = img_c @ pcd_c^T, masked to -inf. grid(16,32)x256.
// Also: zeroes out[] (16384 floats), zeroes cnt[] (16384 u32), zeroes nk,
// and detects bool layout in-block. GEMM body bitwise-identical to the
// verified version.
// =====================================================================
__global__ void coarse_sim_kernel(const float* __restrict__ A,   // [1008,256]
                                  const float* __restrict__ B,   // [1024,256]
                                  const void* __restrict__ maskA,
                                  const void* __restrict__ maskB,
                                  const unsigned int* __restrict__ mskw, // pcd_knn_msk words
                                  float* __restrict__ sim,       // [1008,1024]
                                  float* __restrict__ out0,      // d_out, zeroed here
                                  unsigned int* __restrict__ cnt,// [16384], zeroed here
                                  int* __restrict__ nk) {
    __shared__ __align__(16) float s_a[32][36];
    __shared__ __align__(16) float s_b[32][68];
    const int m0 = blockIdx.y * 32, n0 = blockIdx.x * 64;
    const int tid = threadIdx.x;
    const int tx = tid & 15, ty = tid >> 4;      // ty 0..15 -> 2 rows each
    const int c_lane = tid & 31;
    const int r_base = tid >> 5;                 // 0..7

    // fold-in: zero output + rank counters + compaction counter
    const int bid = blockIdx.y * 16 + blockIdx.x;   // 0..511
    if (tid < 32) out0[bid * 32 + tid] = 0.f;
    if (tid >= 32 && tid < 64) cnt[bid * 32 + (tid - 32)] = 0u;
    if (bid == 0 && tid == 64) *nk = 0;

    // bool-layout probe (consumed at epilogue via __syncthreads_or)
    const bool hit = (mskw[tid] & 0xFFFFFF00u) != 0u;

    const float* pa[4];
    const float* pb[8];
#pragma unroll
    for (int k = 0; k < 4; k++) {
        int m = m0 + r_base + 8 * k;             // 0..31 within tile
        pa[k] = A + (size_t)(m < M_IMG ? m : 0) * CDIM + c_lane;
    }
#pragma unroll
    for (int k = 0; k < 8; k++)
        pb[k] = B + (size_t)(n0 + r_base + 8 * k) * CDIM + c_lane;

    float ra[4], rb[8];
#pragma unroll
    for (int k = 0; k < 4; k++) ra[k] = pa[k][0];
#pragma unroll
    for (int k = 0; k < 8; k++) rb[k] = pb[k][0];
#pragma unroll
    for (int k = 0; k < 4; k++) s_a[c_lane][r_base + 8 * k] = ra[k];
#pragma unroll
    for (int k = 0; k < 8; k++) s_b[c_lane][r_base + 8 * k] = rb[k];
    __syncthreads();

    float acc[2][4];
#pragma unroll
    for (int r = 0; r < 2; r++)
#pragma unroll
        for (int j = 0; j < 4; j++) acc[r][j] = 0.f;

    for (int cit = 0; cit < 8; cit++) {
        if (cit < 7) {
            const int cc = (cit + 1) * 32;
#pragma unroll
            for (int k = 0; k < 4; k++) ra[k] = pa[k][cc];
#pragma unroll
            for (int k = 0; k < 8; k++) rb[k] = pb[k][cc];
        }
#pragma unroll 8
        for (int c = 0; c < 32; c++) {
            float2 av = *(const float2*)&s_a[c][ty * 2];
            float4 bv = *(const float4*)&s_b[c][tx * 4];
            float ar[2] = {av.x, av.y};
            float br[4] = {bv.x, bv.y, bv.z, bv.w};
#pragma unroll
            for (int r = 0; r < 2; r++)
#pragma unroll
                for (int j = 0; j < 4; j++) acc[r][j] += ar[r] * br[j];
        }
        __syncthreads();
        if (cit < 7) {
#pragma unroll
            for (int k = 0; k < 4; k++) s_a[c_lane][r_base + 8 * k] = ra[k];
#pragma unroll
            for (int k = 0; k < 8; k++) s_b[c_lane][r_base + 8 * k] = rb[k];
            __syncthreads();
        }
    }

    const int is_u8 = __syncthreads_or(hit ? 1 : 0);
#pragma unroll
    for (int r = 0; r < 2; r++) {
        int m = m0 + ty * 2 + r;
        if (m < M_IMG) {
            bool ma = mask_val(maskA, m, is_u8);
#pragma unroll
            for (int j = 0; j < 4; j++) {
                int n = n0 + tx * 4 + j;
                bool ok = ma && mask_val(maskB, n, is_u8);
                sim[m * N_PCD + n] = ok ? acc[r][j] : NEG_INF;
            }
        }
    }
}

// =====================================================================
// Kernel 2: fused row top-3 (WITH indices) + FULL-COLUMN top-3.
// grid(1008 + 16)x256. Col blocks own 64 columns over all 1008 rows
// (wave = 64 contiguous floats per row -> coalesced), write col_kth
// directly — no partials, no serial merge downstream.
// =====================================================================
__global__ void kth_kernel(const float* __restrict__ sim,
                           float* __restrict__ rowv3,   // [1008*3]
                           int* __restrict__ rowi3,     // [1008*3]
                           float* __restrict__ col_kth) {// [1024]
    __shared__ float sv[256][3];
    __shared__ int   si[256][3];
    const int tid = threadIdx.x;
    if (blockIdx.x < M_IMG) {
        const float* r = sim + (size_t)blockIdx.x * N_PCD;
        float v0 = NEG_INF, v1 = NEG_INF, v2 = NEG_INF;
        int i0 = 0, i1 = 0, i2 = 0;
#pragma unroll
        for (int e = 0; e < 4; e++) {
            int c = e * 256 + tid;
            t3i_insert(r[c], c, v0, i0, v1, i1, v2, i2);
        }
        sv[tid][0] = v0; sv[tid][1] = v1; sv[tid][2] = v2;
        si[tid][0] = i0; si[tid][1] = i1; si[tid][2] = i2;
        __syncthreads();
        for (int s = 128; s > 0; s >>= 1) {
            if (tid < s) {
                float a0 = sv[tid][0], a1 = sv[tid][1], a2 = sv[tid][2];
                int   j0 = si[tid][0], j1 = si[tid][1], j2 = si[tid][2];
#pragma unroll
                for (int k = 0; k < 3; k++)
                    t3i_insert(sv[tid + s][k], si[tid + s][k],
                               a0, j0, a1, j1, a2, j2);
                sv[tid][0] = a0; sv[tid][1] = a1; sv[tid][2] = a2;
                si[tid][0] = j0; si[tid][1] = j1; si[tid][2] = j2;
            }
            __syncthreads();
        }
        if (tid < 3) {
            rowv3[blockIdx.x * 3 + tid] = sv[0][tid];
            rowi3[blockIdx.x * 3 + tid] = si[0][tid];
        }
    } else {
        const int b = blockIdx.x - M_IMG;        // 0..15
        const int col = b * 64 + (tid & 63);
        const int rr = tid >> 6;                 // 0..3
        float t0 = NEG_INF, t1 = NEG_INF, t2 = NEG_INF;
#pragma unroll 4
        for (int r = rr; r < M_IMG; r += 4)
            top3_insert(sim[(size_t)r * N_PCD + col], t0, t1, t2);
        sv[tid][0] = t0; sv[tid][1] = t1; sv[tid][2] = t2;
        __syncthreads();
        if (tid < 128) {
            float x0, x1, x2;
            top3_merge(sv[tid][0], sv[tid][1], sv[tid][2],
                       sv[tid + 128][0], sv[tid + 128][1], sv[tid + 128][2],
                       x0, x1, x2);
            sv[tid][0] = x0; sv[tid][1] = x1; sv[tid][2] = x2;
        }
        __syncthreads();
        if (tid < 64) {
            float x0, x1, x2;
            top3_merge(sv[tid][0], sv[tid][1], sv[tid][2],
                       sv[tid + 64][0], sv[tid + 64][1], sv[tid + 64][2],
                       x0, x1, x2);
            col_kth[col] = x2;                   // 3rd-largest of full column
        }
    }
}

// =====================================================================
// Kernel 3: parallel top-NUM_CORR selection, grid(12)x1024. Every block
// deterministically rebuilds the SAME compacted candidate key list
// (shfl prefix-sum, e-ascending order, no atomics), then block b
// rank-counts candidates [256b,256b+256) against all K (keys unique ->
// rank exact) and writes sel_idx[rank] for rank<256. Replaces the
// single-block bitonic (67 us, 0.1% VALUBusy) with ~12-block counting.
// =====================================================================
__global__ __launch_bounds__(1024)
void select_kernel(const float* __restrict__ rowv3,
                   const int* __restrict__ rowi3,
                   const float* __restrict__ col_kth,
                   int* __restrict__ sel_idx,
                   int* __restrict__ selK) {
    __shared__ float s_colk[N_PCD];                       // 4 KB
    __shared__ __align__(16) unsigned long long s_key[NCAND]; // 24 KB
    __shared__ int s_part[1024];                          // 4 KB
    __shared__ int s_wsum[16];
    const int tid = threadIdx.x;
    const int lane = tid & 63, w = tid >> 6;

    s_colk[tid] = col_kth[tid];
    __syncthreads();

    // ---- qualify my 3 entries (thread t owns e = 3t..3t+2, t<1008) ----
    unsigned long long k0 = 0, k1 = 0, k2 = 0;
    int f0 = 0, f1 = 0, f2 = 0;
    if (tid < M_IMG) {
#pragma unroll
        for (int s = 0; s < 3; s++) {
            float v = rowv3[tid * 3 + s];
            int n = rowi3[tid * 3 + s];
            if (v > 0.f && v >= s_colk[n]) {
                unsigned int u = __float_as_uint(v);
                unsigned int mono = (u & 0x80000000u) ? ~u : (u | 0x80000000u);
                unsigned long long key =
                    ((unsigned long long)(~mono) << 32)
                    | (unsigned int)(tid * N_PCD + n);
                if (s == 0) { k0 = key; f0 = 1; }
                else if (s == 1) { k1 = key; f1 = 1; }
                else { k2 = key; f2 = 1; }
            }
        }
    }
    const int c = f0 + f1 + f2;

    // ---- block exclusive prefix sum over per-thread counts ----
    int v = c;
#pragma unroll
    for (int d = 1; d < 64; d <<= 1) {
        int o = __shfl_up(v, d);
        if (lane >= d) v += o;
    }
    if (lane == 63) s_wsum[w] = v;
    __syncthreads();
    if (w == 0) {
        int x = (lane < 16) ? s_wsum[lane] : 0;
#pragma unroll
        for (int d = 1; d < 16; d <<= 1) {
            int o = __shfl_up(x, d);
            if (lane >= d) x += o;
        }
        if (lane < 16) s_wsum[lane] = x;
    }
    __syncthreads();
    const int K = s_wsum[15];
    int pos = v - c + (w > 0 ? s_wsum[w - 1] : 0);   // exclusive base, e-order

    if (f0) s_key[pos++] = k0;
    if (f1) s_key[pos++] = k1;
    if (f2) s_key[pos++] = k2;
    __syncthreads();

    if (blockIdx.x == 0 && tid == 0) *selK = (K < NUM_CORR) ? K : NUM_CORR;

    // ---- rank-count: 4 threads per candidate i, quarter-strided j ----
    const int ii = tid & 255, q = tid >> 8;          // wave-uniform q
    const int i = blockIdx.x * 256 + ii;
    const unsigned long long my = (i < K) ? s_key[i] : 0xFFFFFFFFFFFFFFFFull;
    int less = 0;
    for (int j = q; j < K; j += 4)
        less += (s_key[j] < my);                     // LDS broadcast per wave
    s_part[tid] = less;
    __syncthreads();
    if (q == 0 && i < K) {
        int rank = s_part[ii] + s_part[ii + 256] + s_part[ii + 512] + s_part[ii + 768];
        if (rank < NUM_CORR)
            sel_idx[rank] = (int)(s_key[i] & 0xFFFFFFFFull);
    }
}

// =====================================================================
// Kernel 4: fine matching, one block per correspondence. grid(256)x512.
// Mutual top-1 keys are appended compacted AND scored in-place (L2-hot
// rows, exact reference float4 expression). GEMM body unchanged.
// =====================================================================
__global__ void fine_kernel(const float* __restrict__ img_f,   // [76800,256]
                            const float* __restrict__ pcd_f,   // [30000,256]
                            const int* __restrict__ img_knn,   // [1008,64]
                            const int* __restrict__ pcd_knn,   // [1024,64]
                            const void* __restrict__ pcd_msk,  // [1024,64] bool
                            const unsigned int* __restrict__ mskw,
                            const int* __restrict__ sel_idx,
                            const int* __restrict__ selK_ptr,
                            int* __restrict__ nk,
                            unsigned int* __restrict__ ckeys,  // [16384]
                            float* __restrict__ cscore) {      // [16384]
    const int ci = blockIdx.x, tid = threadIdx.x;
    if (ci >= *selK_ptr) return;
    __shared__ int s_ik[KI], s_pk[KP];
    __shared__ unsigned char s_mk[KP];
    __shared__ __align__(16) float s_a[32][68];
    __shared__ __align__(16) float s_b[32][68];
    __shared__ float s_sim[64][65];
    __shared__ int s_rb[64], s_cb[64];
    __shared__ float s_rv[64];

    const bool hit = (mskw[tid & 255] & 0xFFFFFF00u) != 0u;
    int flat = sel_idx[ci];
    int gi = flat >> 10, pi = flat & 1023;
    if (tid < 64) {
        s_ik[tid] = img_knn[gi * KI + tid];
        s_pk[tid] = pcd_knn[pi * KP + tid];
    }
    const int is_u8 = __syncthreads_or(hit ? 1 : 0);
    if (tid < 64)
        s_mk[tid] = mask_val(pcd_msk, pi * KP + tid, is_u8) ? 1 : 0;
    // s_mk is consumed only after the GEMM loop's barriers.

    const int tx = tid & 15, tyy = tid >> 4;     // tyy 0..31 -> 2 rows each
    const int c_lane = tid & 31;
    const int r_base = tid >> 5;                 // 0..15 -> 4 rows each

    const float* pa[4];
    const float* pb[4];
#pragma unroll
    for (int k = 0; k < 4; k++) {
        pa[k] = img_f + (size_t)s_ik[r_base + 16 * k] * CDIM + c_lane;
        pb[k] = pcd_f + (size_t)s_pk[r_base + 16 * k] * CDIM + c_lane;
    }

    float ra[4], rb[4];
#pragma unroll
    for (int k = 0; k < 4; k++) { ra[k] = pa[k][0]; rb[k] = pb[k][0]; }
#pragma unroll
    for (int k = 0; k < 4; k++) {
        s_a[c_lane][r_base + 16 * k] = ra[k];
        s_b[c_lane][r_base + 16 * k] = rb[k];
    }
    __syncthreads();

    float acc[2][4];
#pragma unroll
    for (int r = 0; r < 2; r++)
#pragma unroll
        for (int j = 0; j < 4; j++) acc[r][j] = 0.f;

    for (int cit = 0; cit < 8; cit++) {
        if (cit < 7) {
            const int cc = (cit + 1) * 32;
#pragma unroll
            for (int k = 0; k < 4; k++) { ra[k] = pa[k][cc]; rb[k] = pb[k][cc]; }
        }
#pragma unroll 8
        for (int c = 0; c < 32; c++) {
            float2 av = *(const float2*)&s_a[c][tyy * 2];
            float4 bv = *(const float4*)&s_b[c][tx * 4];
            float ar[2] = {av.x, av.y};
            float br[4] = {bv.x, bv.y, bv.z, bv.w};
#pragma unroll
            for (int r = 0; r < 2; r++)
#pragma unroll
                for (int j = 0; j < 4; j++) acc[r][j] += ar[r] * br[j];
        }
        __syncthreads();
        if (cit < 7) {
#pragma unroll
            for (int k = 0; k < 4; k++) {
                s_a[c_lane][r_base + 16 * k] = ra[k];
                s_b[c_lane][r_base + 16 * k] = rb[k];
            }
            __syncthreads();
        }
    }
#pragma unroll
    for (int r = 0; r < 2; r++) {
        int row = tyy * 2 + r;
#pragma unroll
        for (int j = 0; j < 4; j++) {
            int kp = tx * 4 + j;
            s_sim[row][kp] = (s_mk[kp] != 0) ? acc[r][j] : NEG_INF;
        }
    }
    __syncthreads();

    if (tid < 64) {              // row argmax over kp (first-max semantics)
        float best = NEG_INF; int bi = 0;
        for (int kp = 0; kp < 64; kp++) {
            float v = s_sim[tid][kp];
            if (v > best) { best = v; bi = kp; }
        }
        s_rb[tid] = bi; s_rv[tid] = best;
    } else if (tid < 128) {      // col argmax over ki
        int kp = tid - 64;
        float best = NEG_INF; int bi = 0;
        for (int k2 = 0; k2 < 64; k2++) {
            float v = s_sim[k2][kp];
            if (v > best) { best = v; bi = k2; }
        }
        s_cb[kp] = bi;
    }
    __syncthreads();

    if (tid < 64) {
        int rb2 = s_rb[tid];
        float rv = s_rv[tid];
        if ((s_cb[rb2] == tid) && (rv > 0.f)) {  // mutual top-1 + >FINE_THR
            int ik = s_ik[tid];
            int pk = s_pk[rb2];
            unsigned int key = (unsigned int)ik * KEY_MOD + (unsigned int)pk;
            // score with the exact reference-matching expression (L2-hot rows)
            const float4* a = (const float4*)(img_f + (size_t)ik * CDIM);
            const float4* b = (const float4*)(pcd_f + (size_t)pk * CDIM);
            float s = 0.f;
#pragma unroll 8
            for (int c = 0; c < CDIM / 4; c++) {
                float4 x = a[c], y = b[c];
                s += x.x * y.x + x.y * y.y + x.z * y.z + x.w * y.w;
            }
            int pos = atomicAdd(nk, 1);
            ckeys[pos] = key;                    // key < 2^32, no sentinels
            cscore[pos] = s;
        }
    }
}

// =====================================================================
// Kernel 5: 2-D counting rank over compacted keys. grid(64,64)x256,
// runtime-K early-out. cnt[i] += (less<<16) | eq_before.
// =====================================================================
__global__ void rank_count_kernel(const unsigned int* __restrict__ ckeys,
                                  const int* __restrict__ nk,
                                  unsigned int* __restrict__ cnt) {
    const int K = *nk;
    const int bi = blockIdx.x, bj = blockIdx.y;
    if (bi * 256 >= K || bj * 256 >= K) return;
    __shared__ unsigned int s_k[256];
    const int tid = threadIdx.x;
    const int i = bi * 256 + tid;
    const unsigned int myKey = (i < K) ? ckeys[i] : 0xFFFFFFFFu;
    const int j = bj * 256 + tid;
    s_k[tid] = (j < K) ? ckeys[j] : 0xFFFFFFFFu;   // pad > any real key
    __syncthreads();

    unsigned int less = 0, eqb = 0;
    if (bj < bi) {
#pragma unroll 8
        for (int t = 0; t < 256; t++) {
            unsigned int k = s_k[t];
            less += (k < myKey);
            eqb += (k == myKey);
        }
    } else if (bj == bi) {
#pragma unroll 8
        for (int t = 0; t < 256; t++) {
            unsigned int k = s_k[t];
            less += (k < myKey);
            eqb += (k == myKey) & (t < tid);
        }
    } else {
#pragma unroll 8
        for (int t = 0; t < 256; t++) {
            unsigned int k = s_k[t];
            less += (k < myKey);
        }
    }
    unsigned int v = (less << 16) | eqb;
    if (i < K && v) atomicAdd(&cnt[i], v);
}

// Kernel 6: scatter precomputed scores to ranked slots. grid(64)x256.
__global__ void rank_out_kernel(const unsigned int* __restrict__ cnt,
                                const float* __restrict__ cscore,
                                const int* __restrict__ nk,
                                float* __restrict__ out) {
    const int K = *nk;
    const int i = blockIdx.x * 256 + threadIdx.x;
    if (i >= K) return;
    const unsigned int v = cnt[i];
    if ((v & 0xFFFFu) == 0)                      // first occurrence in list order
        out[v >> 16] = cscore[i];                // rank = less
}

// =====================================================================
extern "C" void kernel_launch(void* const* d_in, const int* in_sizes, int n_in,
                              void* d_out, int out_size, void* d_ws, size_t ws_size,
                              hipStream_t stream) {
    const float* img_c = (const float*)d_in[0];
    const float* pcd_c = (const float*)d_in[1];
    const float* img_f = (const float*)d_in[2];
    const float* pcd_f = (const float*)d_in[3];
    const void* img_mask = d_in[4];
    const void* pcd_mask = d_in[5];
    const int* img_knn = (const int*)d_in[6];
    const int* pcd_knn = (const int*)d_in[7];
    const void* pcd_knn_msk = d_in[8];
    float* out = (float*)d_out;

    // ---- workspace layout (all offsets 4B-aligned) ----
    char* w = (char*)d_ws;
    size_t off = 0;
    float* sim = (float*)(w + off);            off += (size_t)M_IMG * N_PCD * 4; // 4,128,768
    float* rowv3 = (float*)(w + off);          off += M_IMG * 3 * 4;
    int* rowi3 = (int*)(w + off);              off += M_IMG * 3 * 4;
    float* col_kth = (float*)(w + off);        off += N_PCD * 4;
    int* sel_idx = (int*)(w + off);            off += NUM_CORR * 4;
    int* selK = (int*)(w + off);               off += 4;
    int* nk = (int*)(w + off);                 off += 4;
    unsigned int* ckeys = (unsigned int*)(w + off); off += NPAIR * 4;
    float* cscore = (float*)(w + off);         off += NPAIR * 4;
    unsigned int* cnt = (unsigned int*)(w + off);   off += NPAIR * 4;

    const unsigned int* mskw = (const unsigned int*)pcd_knn_msk;

    // 6 dispatches, no memsets, no host-side sync.
    coarse_sim_kernel<<<dim3(16, 32), 256, 0, stream>>>(
        img_c, pcd_c, img_mask, pcd_mask, mskw, sim, out, cnt, nk);
    kth_kernel<<<M_IMG + 16, 256, 0, stream>>>(sim, rowv3, rowi3, col_kth);
    select_kernel<<<12, 1024, 0, stream>>>(rowv3, rowi3, col_kth, sel_idx, selK);
    fine_kernel<<<NUM_CORR, 512, 0, stream>>>(img_f, pcd_f, img_knn, pcd_knn,
                                              pcd_knn_msk, mskw, sel_idx, selK,
                                              nk, ckeys, cscore);
    rank_count_kernel<<<dim3(64, 64), 256, 0, stream>>>(ckeys, nk, cnt);
    rank_out_kernel<<<64, 256, 0, stream>>>(cnt, cscore, nk, out);
}

// Round 4
// 257.819 us; speedup vs baseline: 1.3722x; 1.3722x over previous
//
#include <hip/hip_runtime.h>

// ---- problem constants ----
#define M_IMG 1008
#define N_PCD 1024
#define CDIM  256
#define NI_F  76800
#define NP_F  30000
#define KI    64
#define KP    64
#define NUM_CORR 256
#define NPAIR (NUM_CORR * KI)       // 16384
#define KEY_MOD 30001u
#define NCHUNK 21                   // 21 row-chunks x 48 rows = 1008
#define NCAND (M_IMG * 3)           // 3024 candidate slots
#define NEG_INF (-__builtin_inff())

// bool inputs may arrive as uint8 (numpy bool) or int32 layouts.
__device__ __forceinline__ bool mask_val(const void* p, int i, int is_u8) {
    return is_u8 ? (((const unsigned char*)p)[i] != 0)
                 : (((const int*)p)[i] != 0);
}

// ---- top-3 helpers (values only, multiplicity preserved) ----
__device__ __forceinline__ void top3_insert(float v, float& t0, float& t1, float& t2) {
    if (v > t0) { t2 = t1; t1 = t0; t0 = v; }
    else if (v > t1) { t2 = t1; t1 = v; }
    else if (v > t2) { t2 = v; }
}

__device__ __forceinline__ void top3_merge(float a0, float a1, float a2,
                                           float b0, float b1, float b2,
                                           float& x0, float& x1, float& x2) {
    if (a0 >= b0) {
        x0 = a0;
        if (a1 >= b0) { x1 = a1; x2 = (a2 >= b0) ? a2 : b0; }
        else          { x1 = b0; x2 = (a1 >= b1) ? a1 : b1; }
    } else {
        x0 = b0;
        if (b1 >= a0) { x1 = b1; x2 = (b2 >= a0) ? b2 : a0; }
        else          { x1 = a0; x2 = (b1 >= a1) ? b1 : a1; }
    }
}

// top-3 with index tracking
__device__ __forceinline__ void t3i_insert(float v, int i,
                                           float& v0, int& i0,
                                           float& v1, int& i1,
                                           float& v2, int& i2) {
    if (v > v0) { v2 = v1; i2 = i1; v1 = v0; i1 = i0; v0 = v; i0 = i; }
    else if (v > v1) { v2 = v1; i2 = i1; v1 = v; i1 = i; }
    else if (v > v2) { v2 = v; i2 = i; }
}

// =====================================================================
// Kernel 1: coarse sim = img_c @ pcd_c^T, masked to -inf. grid(16,32)x256.
// Also: zeroes out[]/cnt[]/nk, detects bool layout in-block. GEMM body
// bitwise-identical to the verified version.
// =====================================================================
__global__ void coarse_sim_kernel(const float* __restrict__ A,   // [1008,256]
                                  const float* __restrict__ B,   // [1024,256]
                                  const void* __restrict__ maskA,
                                  const void* __restrict__ maskB,
                                  const unsigned int* __restrict__ mskw, // pcd_knn_msk words
                                  float* __restrict__ sim,       // [1008,1024]
                                  float* __restrict__ out0,      // d_out, zeroed here
                                  unsigned int* __restrict__ cnt,// [16384], zeroed here
                                  int* __restrict__ nk) {
    __shared__ __align__(16) float s_a[32][36];
    __shared__ __align__(16) float s_b[32][68];
    const int m0 = blockIdx.y * 32, n0 = blockIdx.x * 64;
    const int tid = threadIdx.x;
    const int tx = tid & 15, ty = tid >> 4;      // ty 0..15 -> 2 rows each
    const int c_lane = tid & 31;
    const int r_base = tid >> 5;                 // 0..7

    // fold-in: zero output + rank counters + compaction counter
    const int bid = blockIdx.y * 16 + blockIdx.x;   // 0..511
    if (tid < 32) out0[bid * 32 + tid] = 0.f;
    if (tid >= 32 && tid < 64) cnt[bid * 32 + (tid - 32)] = 0u;
    if (bid == 0 && tid == 64) *nk = 0;

    // bool-layout probe (consumed at epilogue via __syncthreads_or)
    const bool hit = (mskw[tid] & 0xFFFFFF00u) != 0u;

    const float* pa[4];
    const float* pb[8];
#pragma unroll
    for (int k = 0; k < 4; k++) {
        int m = m0 + r_base + 8 * k;             // 0..31 within tile
        pa[k] = A + (size_t)(m < M_IMG ? m : 0) * CDIM + c_lane;
    }
#pragma unroll
    for (int k = 0; k < 8; k++)
        pb[k] = B + (size_t)(n0 + r_base + 8 * k) * CDIM + c_lane;

    float ra[4], rb[8];
#pragma unroll
    for (int k = 0; k < 4; k++) ra[k] = pa[k][0];
#pragma unroll
    for (int k = 0; k < 8; k++) rb[k] = pb[k][0];
#pragma unroll
    for (int k = 0; k < 4; k++) s_a[c_lane][r_base + 8 * k] = ra[k];
#pragma unroll
    for (int k = 0; k < 8; k++) s_b[c_lane][r_base + 8 * k] = rb[k];
    __syncthreads();

    float acc[2][4];
#pragma unroll
    for (int r = 0; r < 2; r++)
#pragma unroll
        for (int j = 0; j < 4; j++) acc[r][j] = 0.f;

    for (int cit = 0; cit < 8; cit++) {
        if (cit < 7) {
            const int cc = (cit + 1) * 32;
#pragma unroll
            for (int k = 0; k < 4; k++) ra[k] = pa[k][cc];
#pragma unroll
            for (int k = 0; k < 8; k++) rb[k] = pb[k][cc];
        }
#pragma unroll 8
        for (int c = 0; c < 32; c++) {
            float2 av = *(const float2*)&s_a[c][ty * 2];
            float4 bv = *(const float4*)&s_b[c][tx * 4];
            float ar[2] = {av.x, av.y};
            float br[4] = {bv.x, bv.y, bv.z, bv.w};
#pragma unroll
            for (int r = 0; r < 2; r++)
#pragma unroll
                for (int j = 0; j < 4; j++) acc[r][j] += ar[r] * br[j];
        }
        __syncthreads();
        if (cit < 7) {
#pragma unroll
            for (int k = 0; k < 4; k++) s_a[c_lane][r_base + 8 * k] = ra[k];
#pragma unroll
            for (int k = 0; k < 8; k++) s_b[c_lane][r_base + 8 * k] = rb[k];
            __syncthreads();
        }
    }

    const int is_u8 = __syncthreads_or(hit ? 1 : 0);
#pragma unroll
    for (int r = 0; r < 2; r++) {
        int m = m0 + ty * 2 + r;
        if (m < M_IMG) {
            bool ma = mask_val(maskA, m, is_u8);
#pragma unroll
            for (int j = 0; j < 4; j++) {
                int n = n0 + tx * 4 + j;
                bool ok = ma && mask_val(maskB, n, is_u8);
                sim[m * N_PCD + n] = ok ? acc[r][j] : NEG_INF;
            }
        }
    }
}

// =====================================================================
// Kernel 2: fused row top-3 (WITH indices) + column-PARTIAL top-3.
// grid(1008 + 16*21)x256. Col partials (48 rows x 64 cols per block,
// 336 blocks) keep occupancy high; the 21-chunk merge happens in
// select_kernel (parallel, redundant per block).
// =====================================================================
__global__ void kth_kernel(const float* __restrict__ sim,
                           float* __restrict__ rowv3,   // [1008*3]
                           int* __restrict__ rowi3,     // [1008*3]
                           float* __restrict__ colp) {  // [3][21][1024]
    __shared__ float sv[256][3];
    __shared__ int   si[256][3];
    const int tid = threadIdx.x;
    if (blockIdx.x < M_IMG) {
        const float* r = sim + (size_t)blockIdx.x * N_PCD;
        float v0 = NEG_INF, v1 = NEG_INF, v2 = NEG_INF;
        int i0 = 0, i1 = 0, i2 = 0;
#pragma unroll
        for (int e = 0; e < 4; e++) {
            int c = e * 256 + tid;
            t3i_insert(r[c], c, v0, i0, v1, i1, v2, i2);
        }
        sv[tid][0] = v0; sv[tid][1] = v1; sv[tid][2] = v2;
        si[tid][0] = i0; si[tid][1] = i1; si[tid][2] = i2;
        __syncthreads();
        for (int s = 128; s > 0; s >>= 1) {
            if (tid < s) {
                float a0 = sv[tid][0], a1 = sv[tid][1], a2 = sv[tid][2];
                int   j0 = si[tid][0], j1 = si[tid][1], j2 = si[tid][2];
#pragma unroll
                for (int k = 0; k < 3; k++)
                    t3i_insert(sv[tid + s][k], si[tid + s][k],
                               a0, j0, a1, j1, a2, j2);
                sv[tid][0] = a0; sv[tid][1] = a1; sv[tid][2] = a2;
                si[tid][0] = j0; si[tid][1] = j1; si[tid][2] = j2;
            }
            __syncthreads();
        }
        if (tid < 3) {
            rowv3[blockIdx.x * 3 + tid] = sv[0][tid];
            rowi3[blockIdx.x * 3 + tid] = si[0][tid];
        }
    } else {
        const int b = blockIdx.x - M_IMG;        // 0..335
        const int bx = b & 15, by = b >> 4;      // stripe, row-chunk
        const int c = tid & 63, rr = tid >> 6;
        const int col = bx * 64 + c;
        const int r0 = by * 48;
        float t0 = NEG_INF, t1 = NEG_INF, t2 = NEG_INF;
#pragma unroll
        for (int k = 0; k < 12; k++) {
            float v = sim[(size_t)(r0 + rr + 4 * k) * N_PCD + col];
            top3_insert(v, t0, t1, t2);
        }
        sv[tid][0] = t0; sv[tid][1] = t1; sv[tid][2] = t2;
        __syncthreads();
        if (tid < 128) {
            float x0, x1, x2;
            top3_merge(sv[tid][0], sv[tid][1], sv[tid][2],
                       sv[tid + 128][0], sv[tid + 128][1], sv[tid + 128][2],
                       x0, x1, x2);
            sv[tid][0] = x0; sv[tid][1] = x1; sv[tid][2] = x2;
        }
        __syncthreads();
        if (tid < 64) {
            float x0, x1, x2;
            top3_merge(sv[tid][0], sv[tid][1], sv[tid][2],
                       sv[tid + 64][0], sv[tid + 64][1], sv[tid + 64][2],
                       x0, x1, x2);
            const int base = by * N_PCD + col;
            colp[base] = x0;
            colp[NCHUNK * N_PCD + base] = x1;
            colp[2 * NCHUNK * N_PCD + base] = x2;
        }
    }
}

// =====================================================================
// Kernel 3: parallel top-NUM_CORR selection, grid(12)x1024. Each block:
// (a) redundantly merges the 21 col-partials -> s_colk (thread=column,
//     63 coalesced loads, parallel across 1024 threads);
// (b) deterministically rebuilds the SAME compacted candidate key list
//     (shfl prefix-sum, e-ascending order, no atomics);
// (c) block b rank-counts candidates [256b,256b+256) against all K
//     (keys unique -> rank exact) and writes sel_idx[rank] for rank<256.
// =====================================================================
__global__ __launch_bounds__(1024)
void select_kernel(const float* __restrict__ colp,
                   const float* __restrict__ rowv3,
                   const int* __restrict__ rowi3,
                   int* __restrict__ sel_idx,
                   int* __restrict__ selK) {
    __shared__ float s_colk[N_PCD];                       // 4 KB
    __shared__ __align__(16) unsigned long long s_key[NCAND]; // 24 KB
    __shared__ int s_part[1024];                          // 4 KB
    __shared__ int s_wsum[16];
    const int tid = threadIdx.x;
    const int lane = tid & 63, w = tid >> 6;

    // ---- (a) merge col partials: thread tid owns column tid ----
    {
        float t0 = colp[tid];
        float t1 = colp[NCHUNK * N_PCD + tid];
        float t2 = colp[2 * NCHUNK * N_PCD + tid];
#pragma unroll 4
        for (int ch = 1; ch < NCHUNK; ch++) {
            float b0 = colp[ch * N_PCD + tid];
            float b1 = colp[NCHUNK * N_PCD + ch * N_PCD + tid];
            float b2 = colp[2 * NCHUNK * N_PCD + ch * N_PCD + tid];
            float x0, x1, x2;
            top3_merge(t0, t1, t2, b0, b1, b2, x0, x1, x2);
            t0 = x0; t1 = x1; t2 = x2;
        }
        s_colk[tid] = t2;
    }
    __syncthreads();

    // ---- (b) qualify my 3 entries (thread t owns e = 3t..3t+2, t<1008) ----
    unsigned long long k0 = 0, k1 = 0, k2 = 0;
    int f0 = 0, f1 = 0, f2 = 0;
    if (tid < M_IMG) {
#pragma unroll
        for (int s = 0; s < 3; s++) {
            float v = rowv3[tid * 3 + s];
            int n = rowi3[tid * 3 + s];
            if (v > 0.f && v >= s_colk[n]) {
                unsigned int u = __float_as_uint(v);
                unsigned int mono = (u & 0x80000000u) ? ~u : (u | 0x80000000u);
                unsigned long long key =
                    ((unsigned long long)(~mono) << 32)
                    | (unsigned int)(tid * N_PCD + n);
                if (s == 0) { k0 = key; f0 = 1; }
                else if (s == 1) { k1 = key; f1 = 1; }
                else { k2 = key; f2 = 1; }
            }
        }
    }
    const int c = f0 + f1 + f2;

    // ---- block exclusive prefix sum over per-thread counts ----
    int v = c;
#pragma unroll
    for (int d = 1; d < 64; d <<= 1) {
        int o = __shfl_up(v, d);
        if (lane >= d) v += o;
    }
    if (lane == 63) s_wsum[w] = v;
    __syncthreads();
    if (w == 0) {
        int x = (lane < 16) ? s_wsum[lane] : 0;
#pragma unroll
        for (int d = 1; d < 16; d <<= 1) {
            int o = __shfl_up(x, d);
            if (lane >= d) x += o;
        }
        if (lane < 16) s_wsum[lane] = x;
    }
    __syncthreads();
    const int K = s_wsum[15];
    int pos = v - c + (w > 0 ? s_wsum[w - 1] : 0);   // exclusive base, e-order

    if (f0) s_key[pos++] = k0;
    if (f1) s_key[pos++] = k1;
    if (f2) s_key[pos++] = k2;
    __syncthreads();

    if (blockIdx.x == 0 && tid == 0) *selK = (K < NUM_CORR) ? K : NUM_CORR;

    // ---- (c) rank-count: 4 threads per candidate i, quarter-strided j ----
    const int ii = tid & 255, q = tid >> 8;          // wave-uniform q
    const int i = blockIdx.x * 256 + ii;
    const unsigned long long my = (i < K) ? s_key[i] : 0xFFFFFFFFFFFFFFFFull;
    int less = 0;
    for (int j = q; j < K; j += 4)
        less += (s_key[j] < my);                     // LDS broadcast per wave
    s_part[tid] = less;
    __syncthreads();
    if (q == 0 && i < K) {
        int rank = s_part[ii] + s_part[ii + 256] + s_part[ii + 512] + s_part[ii + 768];
        if (rank < NUM_CORR)
            sel_idx[rank] = (int)(s_key[i] & 0xFFFFFFFFull);
    }
}

// =====================================================================
// Kernel 4: fine matching, one block per correspondence. grid(256)x512.
// Mutual top-1 keys are appended compacted AND scored in-place (L2-hot
// rows, exact reference float4 expression). GEMM body unchanged.
// =====================================================================
__global__ void fine_kernel(const float* __restrict__ img_f,   // [76800,256]
                            const float* __restrict__ pcd_f,   // [30000,256]
                            const int* __restrict__ img_knn,   // [1008,64]
                            const int* __restrict__ pcd_knn,   // [1024,64]
                            const void* __restrict__ pcd_msk,  // [1024,64] bool
                            const unsigned int* __restrict__ mskw,
                            const int* __restrict__ sel_idx,
                            const int* __restrict__ selK_ptr,
                            int* __restrict__ nk,
                            unsigned int* __restrict__ ckeys,  // [16384]
                            float* __restrict__ cscore) {      // [16384]
    const int ci = blockIdx.x, tid = threadIdx.x;
    if (ci >= *selK_ptr) return;
    __shared__ int s_ik[KI], s_pk[KP];
    __shared__ unsigned char s_mk[KP];
    __shared__ __align__(16) float s_a[32][68];
    __shared__ __align__(16) float s_b[32][68];
    __shared__ float s_sim[64][65];
    __shared__ int s_rb[64], s_cb[64];
    __shared__ float s_rv[64];

    const bool hit = (mskw[tid & 255] & 0xFFFFFF00u) != 0u;
    int flat = sel_idx[ci];
    int gi = flat >> 10, pi = flat & 1023;
    if (tid < 64) {
        s_ik[tid] = img_knn[gi * KI + tid];
        s_pk[tid] = pcd_knn[pi * KP + tid];
    }
    const int is_u8 = __syncthreads_or(hit ? 1 : 0);
    if (tid < 64)
        s_mk[tid] = mask_val(pcd_msk, pi * KP + tid, is_u8) ? 1 : 0;
    // s_mk is consumed only after the GEMM loop's barriers.

    const int tx = tid & 15, tyy = tid >> 4;     // tyy 0..31 -> 2 rows each
    const int c_lane = tid & 31;
    const int r_base = tid >> 5;                 // 0..15 -> 4 rows each

    const float* pa[4];
    const float* pb[4];
#pragma unroll
    for (int k = 0; k < 4; k++) {
        pa[k] = img_f + (size_t)s_ik[r_base + 16 * k] * CDIM + c_lane;
        pb[k] = pcd_f + (size_t)s_pk[r_base + 16 * k] * CDIM + c_lane;
    }

    float ra[4], rb[4];
#pragma unroll
    for (int k = 0; k < 4; k++) { ra[k] = pa[k][0]; rb[k] = pb[k][0]; }
#pragma unroll
    for (int k = 0; k < 4; k++) {
        s_a[c_lane][r_base + 16 * k] = ra[k];
        s_b[c_lane][r_base + 16 * k] = rb[k];
    }
    __syncthreads();

    float acc[2][4];
#pragma unroll
    for (int r = 0; r < 2; r++)
#pragma unroll
        for (int j = 0; j < 4; j++) acc[r][j] = 0.f;

    for (int cit = 0; cit < 8; cit++) {
        if (cit < 7) {
            const int cc = (cit + 1) * 32;
#pragma unroll
            for (int k = 0; k < 4; k++) { ra[k] = pa[k][cc]; rb[k] = pb[k][cc]; }
        }
#pragma unroll 8
        for (int c = 0; c < 32; c++) {
            float2 av = *(const float2*)&s_a[c][tyy * 2];
            float4 bv = *(const float4*)&s_b[c][tx * 4];
            float ar[2] = {av.x, av.y};
            float br[4] = {bv.x, bv.y, bv.z, bv.w};
#pragma unroll
            for (int r = 0; r < 2; r++)
#pragma unroll
                for (int j = 0; j < 4; j++) acc[r][j] += ar[r] * br[j];
        }
        __syncthreads();
        if (cit < 7) {
#pragma unroll
            for (int k = 0; k < 4; k++) {
                s_a[c_lane][r_base + 16 * k] = ra[k];
                s_b[c_lane][r_base + 16 * k] = rb[k];
            }
            __syncthreads();
        }
    }
#pragma unroll
    for (int r = 0; r < 2; r++) {
        int row = tyy * 2 + r;
#pragma unroll
        for (int j = 0; j < 4; j++) {
            int kp = tx * 4 + j;
            s_sim[row][kp] = (s_mk[kp] != 0) ? acc[r][j] : NEG_INF;
        }
    }
    __syncthreads();

    if (tid < 64) {              // row argmax over kp (first-max semantics)
        float best = NEG_INF; int bi = 0;
        for (int kp = 0; kp < 64; kp++) {
            float v = s_sim[tid][kp];
            if (v > best) { best = v; bi = kp; }
        }
        s_rb[tid] = bi; s_rv[tid] = best;
    } else if (tid < 128) {      // col argmax over ki
        int kp = tid - 64;
        float best = NEG_INF; int bi = 0;
        for (int k2 = 0; k2 < 64; k2++) {
            float v = s_sim[k2][kp];
            if (v > best) { best = v; bi = k2; }
        }
        s_cb[kp] = bi;
    }
    __syncthreads();

    if (tid < 64) {
        int rb2 = s_rb[tid];
        float rv = s_rv[tid];
        if ((s_cb[rb2] == tid) && (rv > 0.f)) {  // mutual top-1 + >FINE_THR
            int ik = s_ik[tid];
            int pk = s_pk[rb2];
            unsigned int key = (unsigned int)ik * KEY_MOD + (unsigned int)pk;
            // score with the exact reference-matching expression (L2-hot rows)
            const float4* a = (const float4*)(img_f + (size_t)ik * CDIM);
            const float4* b = (const float4*)(pcd_f + (size_t)pk * CDIM);
            float s = 0.f;
#pragma unroll 8
            for (int c = 0; c < CDIM / 4; c++) {
                float4 x = a[c], y = b[c];
                s += x.x * y.x + x.y * y.y + x.z * y.z + x.w * y.w;
            }
            int pos = atomicAdd(nk, 1);
            ckeys[pos] = key;                    // key < 2^32, no sentinels
            cscore[pos] = s;
        }
    }
}

// =====================================================================
// Kernel 5: 2-D counting rank over compacted keys. grid(64,64)x256,
// runtime-K early-out. cnt[i] += (less<<16) | eq_before.
// =====================================================================
__global__ void rank_count_kernel(const unsigned int* __restrict__ ckeys,
                                  const int* __restrict__ nk,
                                  unsigned int* __restrict__ cnt) {
    const int K = *nk;
    const int bi = blockIdx.x, bj = blockIdx.y;
    if (bi * 256 >= K || bj * 256 >= K) return;
    __shared__ unsigned int s_k[256];
    const int tid = threadIdx.x;
    const int i = bi * 256 + tid;
    const unsigned int myKey = (i < K) ? ckeys[i] : 0xFFFFFFFFu;
    const int j = bj * 256 + tid;
    s_k[tid] = (j < K) ? ckeys[j] : 0xFFFFFFFFu;   // pad > any real key
    __syncthreads();

    unsigned int less = 0, eqb = 0;
    if (bj < bi) {
#pragma unroll 8
        for (int t = 0; t < 256; t++) {
            unsigned int k = s_k[t];
            less += (k < myKey);
            eqb += (k == myKey);
        }
    } else if (bj == bi) {
#pragma unroll 8
        for (int t = 0; t < 256; t++) {
            unsigned int k = s_k[t];
            less += (k < myKey);
            eqb += (k == myKey) & (t < tid);
        }
    } else {
#pragma unroll 8
        for (int t = 0; t < 256; t++) {
            unsigned int k = s_k[t];
            less += (k < myKey);
        }
    }
    unsigned int v = (less << 16) | eqb;
    if (i < K && v) atomicAdd(&cnt[i], v);
}

// Kernel 6: scatter precomputed scores to ranked slots. grid(64)x256.
__global__ void rank_out_kernel(const unsigned int* __restrict__ cnt,
                                const float* __restrict__ cscore,
                                const int* __restrict__ nk,
                                float* __restrict__ out) {
    const int K = *nk;
    const int i = blockIdx.x * 256 + threadIdx.x;
    if (i >= K) return;
    const unsigned int v = cnt[i];
    if ((v & 0xFFFFu) == 0)                      // first occurrence in list order
        out[v >> 16] = cscore[i];                // rank = less
}

// =====================================================================
extern "C" void kernel_launch(void* const* d_in, const int* in_sizes, int n_in,
                              void* d_out, int out_size, void* d_ws, size_t ws_size,
                              hipStream_t stream) {
    const float* img_c = (const float*)d_in[0];
    const float* pcd_c = (const float*)d_in[1];
    const float* img_f = (const float*)d_in[2];
    const float* pcd_f = (const float*)d_in[3];
    const void* img_mask = d_in[4];
    const void* pcd_mask = d_in[5];
    const int* img_knn = (const int*)d_in[6];
    const int* pcd_knn = (const int*)d_in[7];
    const void* pcd_knn_msk = d_in[8];
    float* out = (float*)d_out;

    // ---- workspace layout (all offsets 4B-aligned) ----
    char* w = (char*)d_ws;
    size_t off = 0;
    float* sim = (float*)(w + off);            off += (size_t)M_IMG * N_PCD * 4; // 4,128,768
    float* colp = (float*)(w + off);           off += 3 * NCHUNK * N_PCD * 4;    // 258,048
    float* rowv3 = (float*)(w + off);          off += M_IMG * 3 * 4;
    int* rowi3 = (int*)(w + off);              off += M_IMG * 3 * 4;
    int* sel_idx = (int*)(w + off);            off += NUM_CORR * 4;
    int* selK = (int*)(w + off);               off += 4;
    int* nk = (int*)(w + off);                 off += 4;
    unsigned int* ckeys = (unsigned int*)(w + off); off += NPAIR * 4;
    float* cscore = (float*)(w + off);         off += NPAIR * 4;
    unsigned int* cnt = (unsigned int*)(w + off);   off += NPAIR * 4;

    const unsigned int* mskw = (const unsigned int*)pcd_knn_msk;

    // 6 dispatches, no memsets, no host-side sync.
    coarse_sim_kernel<<<dim3(16, 32), 256, 0, stream>>>(
        img_c, pcd_c, img_mask, pcd_mask, mskw, sim, out, cnt, nk);
    kth_kernel<<<M_IMG + 16 * NCHUNK, 256, 0, stream>>>(sim, rowv3, rowi3, colp);
    select_kernel<<<12, 1024, 0, stream>>>(colp, rowv3, rowi3, sel_idx, selK);
    fine_kernel<<<NUM_CORR, 512, 0, stream>>>(img_f, pcd_f, img_knn, pcd_knn,
                                              pcd_knn_msk, mskw, sel_idx, selK,
                                              nk, ckeys, cscore);
    rank_count_kernel<<<dim3(64, 64), 256, 0, stream>>>(ckeys, nk, cnt);
    rank_out_kernel<<<64, 256, 0, stream>>>(cnt, cscore, nk, out);
}